// Round 12
// baseline (210.065 us; speedup 1.0000x reference)
//
#include <hip/hip_runtime.h>

typedef unsigned short u16;
typedef unsigned int u32;
typedef __attribute__((ext_vector_type(8))) short short8;
typedef __attribute__((ext_vector_type(4))) short short4_t;
typedef __attribute__((ext_vector_type(4))) float f32x4;

__device__ __forceinline__ float bf2f(u16 u){ return __uint_as_float(((u32)u)<<16); }
__device__ __forceinline__ u16 f2bf(float f){ u32 x = __float_as_uint(f); return (u16)((x + 0x7FFFu + ((x>>16)&1u)) >> 16); }

// ---------------- workspace layout (bytes) ----------------
#define OFF_FLAG   ((size_t)0)
#define OFF_COUNTS ((size_t)256)
#define OFF_LISTS  ((size_t)4096)                    // 32*4096 int
#define OFF_XN     ((size_t)(1<<20))
#define OFF_CTXN   (OFF_XN    + (size_t)67108864)
#define OFF_WQT    (OFF_CTXN  + (size_t)4194304)
#define OFF_WKVT   (OFF_WQT   + (size_t)2097152)
#define OFF_WOUTT  (OFF_WKVT  + (size_t)2097152)
#define OFF_Q      (OFF_WOUTT + (size_t)2097152)
#define OFF_KV     (OFF_Q     + (size_t)16777216)
#define OFF_ATTN   (OFF_KV    + (size_t)4194304)
#define OFF_VT     (OFF_ATTN  + (size_t)16777216)
#define WS_NEEDED  (OFF_VT    + (size_t)2097152)

// ---------------- mega prep: LN(x) [0,16384) + LN(ctx) [16384,18432)
//                  + weight transposes [18432,21504) + prep [21504] ----------------
__global__ __launch_bounds__(256) void prep_all(const float* __restrict__ x, const float* __restrict__ nw,
                                                const float* __restrict__ nb, u16* __restrict__ xn,
                                                const float* __restrict__ ctx, const float* __restrict__ ncw,
                                                const float* __restrict__ ncb, u16* __restrict__ ctxn,
                                                const float* __restrict__ Wq, const float* __restrict__ Wkv,
                                                const float* __restrict__ Wout, u16* __restrict__ WqT,
                                                u16* __restrict__ WkvT, u16* __restrict__ WoutT,
                                                const int* __restrict__ ml32, int* __restrict__ flag,
                                                int* __restrict__ counts){
  int id = blockIdx.x, tid = threadIdx.x;
  __shared__ float red[8];
  __shared__ float t[32][33];
  __shared__ int nz;
  if (id < 16384){
    constexpr int D = 2048, VEC = 8;
    const float* xr = x + (size_t)id*D;
    float v[VEC];
    #pragma unroll
    for (int i=0;i<VEC;i+=4){
      f32x4 f = *(const f32x4*)(xr + tid*VEC + i);
      v[i]=f[0]; v[i+1]=f[1]; v[i+2]=f[2]; v[i+3]=f[3];
    }
    float s=0.f, sq=0.f;
    #pragma unroll
    for (int i=0;i<VEC;++i){ s += v[i]; sq += v[i]*v[i]; }
    #pragma unroll
    for (int off=32;off;off>>=1){ s += __shfl_xor(s,off,64); sq += __shfl_xor(sq,off,64); }
    int lane = tid&63, wid = tid>>6;
    if (lane==0){ red[wid]=s; red[4+wid]=sq; }
    __syncthreads();
    s  = red[0]+red[1]+red[2]+red[3];
    sq = red[4]+red[5]+red[6]+red[7];
    float mu = s/(float)D;
    float var = sq/(float)D - mu*mu;
    float rs = rsqrtf(var + 1e-5f);
    u16 o[VEC];
    #pragma unroll
    for (int i=0;i<VEC;i+=4){
      f32x4 wv = *(const f32x4*)(nw + tid*VEC + i);
      f32x4 bv = *(const f32x4*)(nb + tid*VEC + i);
      #pragma unroll
      for (int u=0;u<4;++u) o[i+u] = f2bf((v[i+u]-mu)*rs*wv[u] + bv[u]);
    }
    *(short8*)(xn + (size_t)id*D + tid*8) = *(short8*)o;
  } else if (id < 18432){
    constexpr int D = 1024;
    int row = id - 16384;
    const float* xr = ctx + (size_t)row*D;
    f32x4 f = *(const f32x4*)(xr + tid*4);
    float s = f[0]+f[1]+f[2]+f[3];
    float sq = f[0]*f[0]+f[1]*f[1]+f[2]*f[2]+f[3]*f[3];
    #pragma unroll
    for (int off=32;off;off>>=1){ s += __shfl_xor(s,off,64); sq += __shfl_xor(sq,off,64); }
    int lane = tid&63, wid = tid>>6;
    if (lane==0){ red[wid]=s; red[4+wid]=sq; }
    __syncthreads();
    s  = red[0]+red[1]+red[2]+red[3];
    sq = red[4]+red[5]+red[6]+red[7];
    float mu = s/(float)D;
    float var = sq/(float)D - mu*mu;
    float rs = rsqrtf(var + 1e-5f);
    f32x4 wv = *(const f32x4*)(ncw + tid*4);
    f32x4 bv = *(const f32x4*)(ncb + tid*4);
    u16 o[4];
    #pragma unroll
    for (int u=0;u<4;++u) o[u] = f2bf((f[u]-mu)*rs*wv[u] + bv[u]);
    *(short4_t*)(ctxn + (size_t)row*D + tid*4) = *(short4_t*)o;
  } else if (id < 21504){
    int wid2 = id - 18432;
    const float* in; u16* out; int K, N, tile, tx_n;
    if (wid2 < 1024)      { in=Wq;   out=WqT;   K=2048; N=512;  tile=wid2;      tx_n=16; }
    else if (wid2 < 2048) { in=Wkv;  out=WkvT;  K=1024; N=1024; tile=wid2-1024; tx_n=32; }
    else                  { in=Wout; out=WoutT; K=512;  N=2048; tile=wid2-2048; tx_n=64; }
    int n0 = (tile % tx_n)*32, k0 = (tile / tx_n)*32;
    int tx = tid & 31, ty = tid >> 5;
    #pragma unroll
    for (int r=0;r<32;r+=8) t[ty+r][tx] = in[(size_t)(k0+ty+r)*N + n0+tx];
    __syncthreads();
    #pragma unroll
    for (int r=0;r<32;r+=8) out[(size_t)(n0+ty+r)*K + k0+tx] = f2bf(t[tx][ty+r]);
  } else {
    if (tid < 32) counts[tid] = 0;
    if (tid == 0) nz = 0;
    __syncthreads();
    if (tid < 128 && ml32[2*tid+1] != 0) atomicAdd(&nz, 1);
    __syncthreads();
    if (tid == 0) flag[0] = (nz == 0) ? 1 : 0;
  }
}

// ---------------- bf16 GEMM body (m97 128² structure): C = A * B^T ----------------
// MODE: 2 = bf16 out scaled 0.125 (Q), 3 = KV: cols<512 -> kvbuf; cols>=512 -> V^T into vt
template<int MODE>
__device__ __forceinline__ void gemm_body(u16 (*lds)[2][128*32],
                                          const u16* __restrict__ A, const u16* __restrict__ B,
                                          void* __restrict__ Cv, int M, int N, int K, int wg0, int nwg,
                                          u16* __restrict__ vtp){
  int tid = threadIdx.x, lane = tid&63, wid = tid>>6;
  int nbn = N>>7;
  int wg = wg0;
  int cpx = nwg>>3;
  wg = (wg&7)*cpx + (wg>>3);
  int brow = wg/nbn, bcol = wg%nbn;

  auto stage = [&](int buf, int kt){
    #pragma unroll
    for (int i=0;i<2;++i){
      int cb = i*256 + wid*64;
      int c  = cb + lane;
      int row = c>>2, kc = c&3;
      const u16* ga = A + (size_t)(brow*128+row)*K + kt*32 + kc*8;
      __builtin_amdgcn_global_load_lds((const __attribute__((address_space(1))) u32*)ga,
          (__attribute__((address_space(3))) u32*)&lds[buf][0][cb*8], 16, 0, 0);
      const u16* gb = B + (size_t)(bcol*128+row)*K + kt*32 + kc*8;
      __builtin_amdgcn_global_load_lds((const __attribute__((address_space(1))) u32*)gb,
          (__attribute__((address_space(3))) u32*)&lds[buf][1][cb*8], 16, 0, 0);
    }
  };

  int wm = wid>>1, wn = wid&1;
  f32x4 acc[4][4] = {};
  int nkt = K>>5;
  stage(0,0);
  __syncthreads();
  for (int kt=0; kt<nkt; ++kt){
    int cur = kt&1;
    if (kt+1<nkt) stage(cur^1, kt+1);
    short8 af[4], bfr[4];
    int r = lane&15, kq = lane>>4;
    #pragma unroll
    for (int mi=0;mi<4;++mi) af[mi]  = *(const short8*)&lds[cur][0][(wm*64+mi*16+r)*32 + kq*8];
    #pragma unroll
    for (int ni=0;ni<4;++ni) bfr[ni] = *(const short8*)&lds[cur][1][(wn*64+ni*16+r)*32 + kq*8];
    #pragma unroll
    for (int mi=0;mi<4;++mi)
      #pragma unroll
      for (int ni=0;ni<4;++ni)
        acc[mi][ni] = __builtin_amdgcn_mfma_f32_16x16x32_bf16(af[mi], bfr[ni], acc[mi][ni], 0,0,0);
    __syncthreads();
  }
  int r4 = (lane>>4)*4, cc = lane&15;
  #pragma unroll
  for (int mi=0;mi<4;++mi){
    int rowb = brow*128 + wm*64 + mi*16 + r4;
    #pragma unroll
    for (int ni=0;ni<4;++ni){
      int col = bcol*128 + wn*64 + ni*16 + cc;
      #pragma unroll
      for (int rr=0;rr<4;++rr){
        int row = rowb + rr;
        float val = acc[mi][ni][rr];
        if (MODE==2) ((u16*)Cv)[(size_t)row*N+col] = f2bf(val*0.125f);
        else {
          if (col < 512)  ((u16*)Cv)[(size_t)row*N+col] = f2bf(val);
          else {
            int hv = (col-512)>>6, d = (col-512)&63;
            vtp[(size_t)((row>>6)*8 + hv)*4096 + d*64 + (row&63)] = f2bf(val);
          }
        }
      }
    }
  }
}

// merged Q-GEMM [0,512) + KV-GEMM-with-fused-V^T [512,640) + bucket [640,704)
__global__ __launch_bounds__(256) void gemm_qkv(const u16* __restrict__ xn, const u16* __restrict__ WqT,
                                                u16* __restrict__ qbuf, const u16* __restrict__ ctxn,
                                                const u16* __restrict__ WkvT, u16* __restrict__ kvbuf,
                                                u16* __restrict__ vtbuf,
                                                const int* __restrict__ ml32, const int* __restrict__ flag,
                                                int* __restrict__ counts, int* __restrict__ lists){
  __shared__ __align__(16) u16 lds[2][2][128*32];
  __shared__ int lc[32], lbase[32];
  if (blockIdx.x < 512)      gemm_body<2>(lds, xn,   WqT,  qbuf,  16384, 512,  2048, blockIdx.x,     512, nullptr);
  else if (blockIdx.x < 640) gemm_body<3>(lds, ctxn, WkvT, kvbuf, 2048,  1024, 1024, blockIdx.x-512, 128, vtbuf);
  else {
    int bid = blockIdx.x - 640, tid = threadIdx.x;
    if (tid < 32) lc[tid] = 0;
    __syncthreads();
    int i = bid*256 + tid;
    int loc = flag[0] ? ml32[2*i] : ml32[i];
    int blk = (i>>12)*8 + loc;
    int lpos = atomicAdd(&lc[blk], 1);
    __syncthreads();
    if (tid < 32 && lc[tid] > 0) lbase[tid] = atomicAdd(&counts[tid], lc[tid]);
    __syncthreads();
    lists[blk*4096 + lbase[blk] + lpos] = i & 4095;
  }
}

// ---------------- 8-phase 256x256 out-GEMM (T3+T4, linear LDS, m198 structure) ----------------
// C[16384][2048] f32 = A[16384][512] bf16 * B^T (B=[2048][512] bf16). BK=64, 8 waves (2Mx4N).
// Stage order per K-tile: [B0,B1,B2,B3,A0,A2,A1,A3] (2 chunks/phase). Counted waits:
// boundary vmcnt(2) (6 oldest = B0-B3,A0,A2 of incoming tile done), mid-tile vmcnt(4)
// before phase-2 ds_reads (forces A1,A3), tail vmcnt(0). Raw s_barrier (no vmcnt drain).
__global__ __launch_bounds__(512) void gemm_out8(const u16* __restrict__ A, const u16* __restrict__ B,
                                                 float* __restrict__ C){
  __shared__ __align__(16) u16 lA[2][16384];
  __shared__ __align__(16) u16 lB[2][16384];
  constexpr int N = 2048, K = 512, NKT = 8;
  int tid = threadIdx.x, lane = tid&63;
  int wid = tid>>6, wm = wid>>2, wn = wid&3;
  int wg = blockIdx.x;
  int cpx = 512>>3;                 // 64; grid=512 %8==0 -> bijective XCD swizzle
  wg = (wg&7)*cpx + (wg>>3);
  int brow = wg>>3, bcol = wg&7;    // 64 x 8 tiles of 256x256

  const u16* Abase = A + (size_t)(brow*256 + (tid>>3))*K + (tid&7)*8;
  const u16* Bbase = B + (size_t)(bcol*256 + (tid>>3))*K + (tid&7)*8;

  auto stage_pos = [&](int buf, int kt, int pos){
    if (pos < 4){
      const u16* g = Bbase + (size_t)(pos*64)*K + kt*64;
      __builtin_amdgcn_global_load_lds((const __attribute__((address_space(1))) u32*)g,
          (__attribute__((address_space(3))) u32*)&lB[buf][pos*4096 + tid*8], 16, 0, 0);
    } else {
      int ci = (pos==4) ? 0 : (pos==5) ? 2 : (pos==6) ? 1 : 3;   // A order: A0,A2,A1,A3
      const u16* g = Abase + (size_t)(ci*64)*K + kt*64;
      __builtin_amdgcn_global_load_lds((const __attribute__((address_space(1))) u32*)g,
          (__attribute__((address_space(3))) u32*)&lA[buf][ci*4096 + tid*8], 16, 0, 0);
    }
  };

  // prologue: stage tile 0 fully, drain, barrier
  #pragma unroll
  for (int pos=0; pos<8; ++pos) stage_pos(0, 0, pos);
  asm volatile("s_waitcnt vmcnt(0)" ::: "memory");
  __builtin_amdgcn_s_barrier();

  f32x4 acc[8][4] = {};
  int r = lane&15, kq = lane>>4;

  for (int kt=0; kt<NKT; ++kt){
    int cur = kt&1;
    const u16* la = &lA[cur][0];
    const u16* lb = &lB[cur][0];
    bool has_next = (kt+1 < NKT);
    short8 bf8[4][2];
    #pragma unroll
    for (int p=0;p<4;++p){
      if (p==2){
        if (has_next) asm volatile("s_waitcnt vmcnt(4)" ::: "memory");
        else          asm volatile("s_waitcnt vmcnt(0)" ::: "memory");
      }
      if (has_next){
        stage_pos(cur^1, kt+1, 2*p);
        stage_pos(cur^1, kt+1, 2*p+1);
      }
      if (p==0){
        #pragma unroll
        for (int nt=0;nt<4;++nt)
          #pragma unroll
          for (int ks=0;ks<2;++ks)
            bf8[nt][ks] = *(const short8*)&lb[(wn*64+nt*16+r)*64 + ks*32 + kq*8];
      }
      short8 af8[2][2];
      #pragma unroll
      for (int j=0;j<2;++j)
        #pragma unroll
        for (int ks=0;ks<2;++ks)
          af8[j][ks] = *(const short8*)&la[(wm*128+(2*p+j)*16+r)*64 + ks*32 + kq*8];
      __builtin_amdgcn_s_barrier();
      __builtin_amdgcn_s_setprio(1);
      #pragma unroll
      for (int j=0;j<2;++j)
        #pragma unroll
        for (int nt=0;nt<4;++nt)
          #pragma unroll
          for (int ks=0;ks<2;++ks)
            acc[2*p+j][nt] = __builtin_amdgcn_mfma_f32_16x16x32_bf16(af8[j][ks], bf8[nt][ks], acc[2*p+j][nt], 0,0,0);
      __builtin_amdgcn_s_setprio(0);
      __builtin_amdgcn_s_barrier();
    }
    if (has_next){
      asm volatile("s_waitcnt lgkmcnt(0)" ::: "memory");
      __builtin_amdgcn_sched_barrier(0);
      asm volatile("s_waitcnt vmcnt(2)" ::: "memory");
      __builtin_amdgcn_s_barrier();
    }
  }

  int colb = bcol*256 + wn*64;
  int rowb = brow*256 + wm*128;
  #pragma unroll
  for (int mt=0;mt<8;++mt)
    #pragma unroll
    for (int nt=0;nt<4;++nt)
      #pragma unroll
      for (int rr=0;rr<4;++rr)
        C[(size_t)(rowb + mt*16 + kq*4 + rr)*N + colb + nt*16 + r] = acc[mt][nt][rr];
}

// ---------------- MFMA bucketed attention, v5 + setprio (unchanged from r11) ----------------
__global__ __launch_bounds__(512) void attn_mfma5(const u16* __restrict__ qb, const u16* __restrict__ kvb,
                                                  const u16* __restrict__ vt, u16* __restrict__ ob,
                                                  const int* __restrict__ counts, const int* __restrict__ lists){
  int bl = blockIdx.y, chunk = blockIdx.x;
  int cnt = counts[bl];
  int q0 = chunk*32;
  if (q0 >= cnt) return;
  int b = bl>>3, loc = bl&7;
  int tid = threadIdx.x, lane = tid&63, h = tid>>6;
  __shared__ u16 qs[32][520];
  int r = lane&15, g = lane>>4;

  const u16* kbase = kvb + (size_t)(b*512 + loc*64)*1024 + h*64;
  short8 kfr[4][2];
  #pragma unroll
  for (int nt=0;nt<4;++nt){
    const u16* krow = kbase + (size_t)(nt*16 + r)*1024;
    kfr[nt][0] = *(const short8*)(krow + g*8);
    kfr[nt][1] = *(const short8*)(krow + 32 + g*8);
  }
  const u16* vbase = vt + (size_t)(bl*8 + h)*4096;
  short8 vf[2][4];
  #pragma unroll
  for (int nt=0;nt<4;++nt){
    const u16* vrow = vbase + (size_t)(nt*16 + r)*64;
    vf[0][nt] = *(const short8*)(vrow + g*8);
    vf[1][nt] = *(const short8*)(vrow + 32 + g*8);
  }

  const u16* qbase = qb + (size_t)(b*4096)*512;
  #pragma unroll
  for (int p=0;p<4;++p){
    int c = p*512 + tid;
    int row = c>>6, cc = c&63;
    int qq = (q0 + row < cnt) ? lists[bl*4096 + q0 + row] : -1;
    if (qq >= 0)
      *(short8*)&qs[row][cc*8] = *(const short8*)(qbase + (size_t)qq*512 + cc*8);
  }
  __syncthreads();

  short8 qf[2][2];
  #pragma unroll
  for (int mt=0;mt<2;++mt){
    qf[mt][0] = *(const short8*)&qs[mt*16+r][h*64 + g*8];
    qf[mt][1] = *(const short8*)&qs[mt*16+r][h*64 + 32 + g*8];
  }

  f32x4 acc[2][4] = {};
  __builtin_amdgcn_s_setprio(1);
  #pragma unroll
  for (int mt=0;mt<2;++mt)
    #pragma unroll
    for (int nt=0;nt<4;++nt){
      acc[mt][nt] = __builtin_amdgcn_mfma_f32_16x16x32_bf16(qf[mt][0], kfr[nt][0], acc[mt][nt], 0,0,0);
      acc[mt][nt] = __builtin_amdgcn_mfma_f32_16x16x32_bf16(qf[mt][1], kfr[nt][1], acc[mt][nt], 0,0,0);
    }
  __builtin_amdgcn_s_setprio(0);

  #pragma unroll
  for (int mt=0;mt<2;++mt){
    #pragma unroll
    for (int rr=0;rr<4;++rr){
      float m = fmaxf(fmaxf(acc[mt][0][rr], acc[mt][1][rr]), fmaxf(acc[mt][2][rr], acc[mt][3][rr]));
      #pragma unroll
      for (int off=1;off<16;off<<=1) m = fmaxf(m, __shfl_xor(m, off));
      float e0 = __expf(acc[mt][0][rr]-m), e1 = __expf(acc[mt][1][rr]-m);
      float e2 = __expf(acc[mt][2][rr]-m), e3 = __expf(acc[mt][3][rr]-m);
      float sum = (e0+e1)+(e2+e3);
      #pragma unroll
      for (int off=1;off<16;off<<=1) sum += __shfl_xor(sum, off);
      float rs = 1.0f/sum;
      int row = mt*16 + g*4 + rr;
      qs[row][h*64 +  0 + r] = f2bf(e0*rs);
      qs[row][h*64 + 16 + r] = f2bf(e1*rs);
      qs[row][h*64 + 32 + r] = f2bf(e2*rs);
      qs[row][h*64 + 48 + r] = f2bf(e3*rs);
    }
  }

  f32x4 oacc[2][4] = {};
  #pragma unroll
  for (int mt=0;mt<2;++mt){
    short8 pa0 = *(const short8*)&qs[mt*16 + r][h*64 + g*8];
    short8 pa1 = *(const short8*)&qs[mt*16 + r][h*64 + 32 + g*8];
    __builtin_amdgcn_s_setprio(1);
    #pragma unroll
    for (int nt=0;nt<4;++nt){
      oacc[mt][nt] = __builtin_amdgcn_mfma_f32_16x16x32_bf16(pa0, vf[0][nt], oacc[mt][nt], 0,0,0);
      oacc[mt][nt] = __builtin_amdgcn_mfma_f32_16x16x32_bf16(pa1, vf[1][nt], oacc[mt][nt], 0,0,0);
    }
    __builtin_amdgcn_s_setprio(0);
  }

  #pragma unroll
  for (int mt=0;mt<2;++mt)
    #pragma unroll
    for (int rr=0;rr<4;++rr){
      int row = mt*16 + g*4 + rr;
      #pragma unroll
      for (int nt=0;nt<4;++nt)
        qs[row][h*64 + nt*16 + r] = f2bf(oacc[mt][nt][rr]);
    }
  __syncthreads();

  #pragma unroll
  for (int p=0;p<4;++p){
    int c = p*512 + tid;
    int row = c>>6, cc = c&63;
    int qq = (q0 + row < cnt) ? lists[bl*4096 + q0 + row] : -1;
    if (qq >= 0)
      *(short8*)(ob + ((size_t)(b*4096) + qq)*512 + cc*8) = *(const short8*)&qs[row][cc*8];
  }
}

extern "C" void kernel_launch(void* const* d_in, const int* in_sizes, int n_in,
                              void* d_out, int out_size, void* d_ws, size_t ws_size,
                              hipStream_t stream) {
  const float* x    = (const float*)d_in[0];
  const float* ctx  = (const float*)d_in[1];
  const int*   ml   = (const int*)d_in[2];
  const float* nw   = (const float*)d_in[3];
  const float* nb   = (const float*)d_in[4];
  const float* ncw  = (const float*)d_in[5];
  const float* ncb  = (const float*)d_in[6];
  const float* Wq   = (const float*)d_in[7];
  const float* Wkv  = (const float*)d_in[8];
  const float* Wout = (const float*)d_in[9];
  float* out = (float*)d_out;
  char* ws = (char*)d_ws;
  if (ws_size < WS_NEEDED) return;   // fail loudly (output stays poisoned)

  int* flag   = (int*)(ws + OFF_FLAG);
  int* counts = (int*)(ws + OFF_COUNTS);
  int* lists  = (int*)(ws + OFF_LISTS);
  u16* xn     = (u16*)(ws + OFF_XN);
  u16* ctxn   = (u16*)(ws + OFF_CTXN);
  u16* WqT    = (u16*)(ws + OFF_WQT);
  u16* WkvT   = (u16*)(ws + OFF_WKVT);
  u16* WoutT  = (u16*)(ws + OFF_WOUTT);
  u16* qbuf   = (u16*)(ws + OFF_Q);
  u16* kvbuf  = (u16*)(ws + OFF_KV);
  u16* attn_o = (u16*)(ws + OFF_ATTN);
  u16* vtbuf  = (u16*)(ws + OFF_VT);

  prep_all<<<21505,256,0,stream>>>(x, nw, nb, xn, ctx, ncw, ncb, ctxn,
                                   Wq, Wkv, Wout, WqT, WkvT, WoutT, ml, flag, counts);
  gemm_qkv<<<704,256,0,stream>>>(xn, WqT, qbuf, ctxn, WkvT, kvbuf, vtbuf, ml, flag, counts, lists);
  attn_mfma5<<<dim3(128,32),512,0,stream>>>(qbuf, kvbuf, vtbuf, attn_o, counts, lists);
  gemm_out8<<<512,512,0,stream>>>(attn_o, WoutT, out);
}

// Round 13
// 197.107 us; speedup vs baseline: 1.0657x; 1.0657x over previous
//
#include <hip/hip_runtime.h>

typedef unsigned short u16;
typedef unsigned int u32;
typedef __attribute__((ext_vector_type(8))) short short8;
typedef __attribute__((ext_vector_type(4))) short short4_t;
typedef __attribute__((ext_vector_type(4))) float f32x4;

__device__ __forceinline__ float bf2f(u16 u){ return __uint_as_float(((u32)u)<<16); }
__device__ __forceinline__ u16 f2bf(float f){ u32 x = __float_as_uint(f); return (u16)((x + 0x7FFFu + ((x>>16)&1u)) >> 16); }

// ---------------- workspace layout (bytes) ----------------
#define OFF_FLAG   ((size_t)0)
#define OFF_COUNTS ((size_t)256)
#define OFF_LISTS  ((size_t)4096)                    // 32*4096 int
#define OFF_XN     ((size_t)(1<<20))
#define OFF_CTXN   (OFF_XN    + (size_t)67108864)
#define OFF_WQT    (OFF_CTXN  + (size_t)4194304)
#define OFF_WKVT   (OFF_WQT   + (size_t)2097152)
#define OFF_WOUTT  (OFF_WKVT  + (size_t)2097152)
#define OFF_Q      (OFF_WOUTT + (size_t)2097152)
#define OFF_KV     (OFF_Q     + (size_t)16777216)
#define OFF_ATTN   (OFF_KV    + (size_t)4194304)
#define OFF_VT     (OFF_ATTN  + (size_t)16777216)
#define WS_NEEDED  (OFF_VT    + (size_t)2097152)

// ---------------- mega prep: LN(x) [0,16384) + LN(ctx) [16384,18432)
//                  + weight transposes [18432,21504) + prep [21504] ----------------
__global__ __launch_bounds__(256) void prep_all(const float* __restrict__ x, const float* __restrict__ nw,
                                                const float* __restrict__ nb, u16* __restrict__ xn,
                                                const float* __restrict__ ctx, const float* __restrict__ ncw,
                                                const float* __restrict__ ncb, u16* __restrict__ ctxn,
                                                const float* __restrict__ Wq, const float* __restrict__ Wkv,
                                                const float* __restrict__ Wout, u16* __restrict__ WqT,
                                                u16* __restrict__ WkvT, u16* __restrict__ WoutT,
                                                const int* __restrict__ ml32, int* __restrict__ flag,
                                                int* __restrict__ counts){
  int id = blockIdx.x, tid = threadIdx.x;
  __shared__ float red[8];
  __shared__ float t[32][33];
  __shared__ int nz;
  if (id < 16384){
    constexpr int D = 2048, VEC = 8;
    const float* xr = x + (size_t)id*D;
    float v[VEC];
    #pragma unroll
    for (int i=0;i<VEC;i+=4){
      f32x4 f = *(const f32x4*)(xr + tid*VEC + i);
      v[i]=f[0]; v[i+1]=f[1]; v[i+2]=f[2]; v[i+3]=f[3];
    }
    float s=0.f, sq=0.f;
    #pragma unroll
    for (int i=0;i<VEC;++i){ s += v[i]; sq += v[i]*v[i]; }
    #pragma unroll
    for (int off=32;off;off>>=1){ s += __shfl_xor(s,off,64); sq += __shfl_xor(sq,off,64); }
    int lane = tid&63, wid = tid>>6;
    if (lane==0){ red[wid]=s; red[4+wid]=sq; }
    __syncthreads();
    s  = red[0]+red[1]+red[2]+red[3];
    sq = red[4]+red[5]+red[6]+red[7];
    float mu = s/(float)D;
    float var = sq/(float)D - mu*mu;
    float rs = rsqrtf(var + 1e-5f);
    u16 o[VEC];
    #pragma unroll
    for (int i=0;i<VEC;i+=4){
      f32x4 wv = *(const f32x4*)(nw + tid*VEC + i);
      f32x4 bv = *(const f32x4*)(nb + tid*VEC + i);
      #pragma unroll
      for (int u=0;u<4;++u) o[i+u] = f2bf((v[i+u]-mu)*rs*wv[u] + bv[u]);
    }
    *(short8*)(xn + (size_t)id*D + tid*8) = *(short8*)o;
  } else if (id < 18432){
    constexpr int D = 1024;
    int row = id - 16384;
    const float* xr = ctx + (size_t)row*D;
    f32x4 f = *(const f32x4*)(xr + tid*4);
    float s = f[0]+f[1]+f[2]+f[3];
    float sq = f[0]*f[0]+f[1]*f[1]+f[2]*f[2]+f[3]*f[3];
    #pragma unroll
    for (int off=32;off;off>>=1){ s += __shfl_xor(s,off,64); sq += __shfl_xor(sq,off,64); }
    int lane = tid&63, wid = tid>>6;
    if (lane==0){ red[wid]=s; red[4+wid]=sq; }
    __syncthreads();
    s  = red[0]+red[1]+red[2]+red[3];
    sq = red[4]+red[5]+red[6]+red[7];
    float mu = s/(float)D;
    float var = sq/(float)D - mu*mu;
    float rs = rsqrtf(var + 1e-5f);
    f32x4 wv = *(const f32x4*)(ncw + tid*4);
    f32x4 bv = *(const f32x4*)(ncb + tid*4);
    u16 o[4];
    #pragma unroll
    for (int u=0;u<4;++u) o[u] = f2bf((f[u]-mu)*rs*wv[u] + bv[u]);
    *(short4_t*)(ctxn + (size_t)row*D + tid*4) = *(short4_t*)o;
  } else if (id < 21504){
    int wid2 = id - 18432;
    const float* in; u16* out; int K, N, tile, tx_n;
    if (wid2 < 1024)      { in=Wq;   out=WqT;   K=2048; N=512;  tile=wid2;      tx_n=16; }
    else if (wid2 < 2048) { in=Wkv;  out=WkvT;  K=1024; N=1024; tile=wid2-1024; tx_n=32; }
    else                  { in=Wout; out=WoutT; K=512;  N=2048; tile=wid2-2048; tx_n=64; }
    int n0 = (tile % tx_n)*32, k0 = (tile / tx_n)*32;
    int tx = tid & 31, ty = tid >> 5;
    #pragma unroll
    for (int r=0;r<32;r+=8) t[ty+r][tx] = in[(size_t)(k0+ty+r)*N + n0+tx];
    __syncthreads();
    #pragma unroll
    for (int r=0;r<32;r+=8) out[(size_t)(n0+ty+r)*K + k0+tx] = f2bf(t[tx][ty+r]);
  } else {
    if (tid < 32) counts[tid] = 0;
    if (tid == 0) nz = 0;
    __syncthreads();
    if (tid < 128 && ml32[2*tid+1] != 0) atomicAdd(&nz, 1);
    __syncthreads();
    if (tid == 0) flag[0] = (nz == 0) ? 1 : 0;
  }
}

// ---------------- bf16 GEMM body (m97 128² structure): C = A * B^T ----------------
// MODE: 0 = f32 out (non-temporal streaming store), 2 = bf16 out scaled 0.125 (Q),
//       3 = KV: cols<512 -> kvbuf; cols>=512 -> V^T into vt[bl][h][d][key]
template<int MODE>
__device__ __forceinline__ void gemm_body(u16 (*lds)[2][128*32],
                                          const u16* __restrict__ A, const u16* __restrict__ B,
                                          void* __restrict__ Cv, int M, int N, int K, int wg0, int nwg,
                                          u16* __restrict__ vtp){
  int tid = threadIdx.x, lane = tid&63, wid = tid>>6;
  int nbn = N>>7;
  int wg = wg0;
  int cpx = nwg>>3;                 // nwg %8==0 -> bijective XCD swizzle
  wg = (wg&7)*cpx + (wg>>3);
  int brow = wg/nbn, bcol = wg%nbn;

  auto stage = [&](int buf, int kt){
    #pragma unroll
    for (int i=0;i<2;++i){
      int cb = i*256 + wid*64;      // wave-uniform chunk base
      int c  = cb + lane;
      int row = c>>2, kc = c&3;
      const u16* ga = A + (size_t)(brow*128+row)*K + kt*32 + kc*8;
      __builtin_amdgcn_global_load_lds((const __attribute__((address_space(1))) u32*)ga,
          (__attribute__((address_space(3))) u32*)&lds[buf][0][cb*8], 16, 0, 0);
      const u16* gb = B + (size_t)(bcol*128+row)*K + kt*32 + kc*8;
      __builtin_amdgcn_global_load_lds((const __attribute__((address_space(1))) u32*)gb,
          (__attribute__((address_space(3))) u32*)&lds[buf][1][cb*8], 16, 0, 0);
    }
  };

  int wm = wid>>1, wn = wid&1;
  f32x4 acc[4][4] = {};
  int nkt = K>>5;
  stage(0,0);
  __syncthreads();
  for (int kt=0; kt<nkt; ++kt){
    int cur = kt&1;
    if (kt+1<nkt) stage(cur^1, kt+1);
    short8 af[4], bfr[4];
    int r = lane&15, kq = lane>>4;
    #pragma unroll
    for (int mi=0;mi<4;++mi) af[mi]  = *(const short8*)&lds[cur][0][(wm*64+mi*16+r)*32 + kq*8];
    #pragma unroll
    for (int ni=0;ni<4;++ni) bfr[ni] = *(const short8*)&lds[cur][1][(wn*64+ni*16+r)*32 + kq*8];
    #pragma unroll
    for (int mi=0;mi<4;++mi)
      #pragma unroll
      for (int ni=0;ni<4;++ni)
        acc[mi][ni] = __builtin_amdgcn_mfma_f32_16x16x32_bf16(af[mi], bfr[ni], acc[mi][ni], 0,0,0);
    __syncthreads();
  }
  int r4 = (lane>>4)*4, cc = lane&15;
  #pragma unroll
  for (int mi=0;mi<4;++mi){
    int rowb = brow*128 + wm*64 + mi*16 + r4;
    #pragma unroll
    for (int ni=0;ni<4;++ni){
      int col = bcol*128 + wn*64 + ni*16 + cc;
      #pragma unroll
      for (int rr=0;rr<4;++rr){
        int row = rowb + rr;
        float val = acc[mi][ni][rr];
        if (MODE==0)      __builtin_nontemporal_store(val, &((float*)Cv)[(size_t)row*N+col]);
        else if (MODE==2) ((u16*)Cv)[(size_t)row*N+col] = f2bf(val*0.125f);
        else {
          if (col < 512)  ((u16*)Cv)[(size_t)row*N+col] = f2bf(val);
          else {
            int hv = (col-512)>>6, d = (col-512)&63;
            vtp[(size_t)((row>>6)*8 + hv)*4096 + d*64 + (row&63)] = f2bf(val);
          }
        }
      }
    }
  }
}

// merged Q-GEMM [0,512) + KV-GEMM-with-fused-V^T [512,640) + bucket [640,704)
__global__ __launch_bounds__(256) void gemm_qkv(const u16* __restrict__ xn, const u16* __restrict__ WqT,
                                                u16* __restrict__ qbuf, const u16* __restrict__ ctxn,
                                                const u16* __restrict__ WkvT, u16* __restrict__ kvbuf,
                                                u16* __restrict__ vtbuf,
                                                const int* __restrict__ ml32, const int* __restrict__ flag,
                                                int* __restrict__ counts, int* __restrict__ lists){
  __shared__ __align__(16) u16 lds[2][2][128*32];
  __shared__ int lc[32], lbase[32];
  if (blockIdx.x < 512)      gemm_body<2>(lds, xn,   WqT,  qbuf,  16384, 512,  2048, blockIdx.x,     512, nullptr);
  else if (blockIdx.x < 640) gemm_body<3>(lds, ctxn, WkvT, kvbuf, 2048,  1024, 1024, blockIdx.x-512, 128, vtbuf);
  else {
    int bid = blockIdx.x - 640, tid = threadIdx.x;
    if (tid < 32) lc[tid] = 0;
    __syncthreads();
    int i = bid*256 + tid;
    int loc = flag[0] ? ml32[2*i] : ml32[i];
    int blk = (i>>12)*8 + loc;
    int lpos = atomicAdd(&lc[blk], 1);
    __syncthreads();
    if (tid < 32 && lc[tid] > 0) lbase[tid] = atomicAdd(&counts[tid], lc[tid]);
    __syncthreads();
    lists[blk*4096 + lbase[blk] + lpos] = i & 4095;
  }
}

// out-GEMM: standalone (f32 dense, nt-store epilogue)
__global__ __launch_bounds__(256) void gemm_out(const u16* __restrict__ A, const u16* __restrict__ B,
                                                float* __restrict__ C){
  __shared__ __align__(16) u16 lds[2][2][128*32];
  gemm_body<0>(lds, A, B, C, 16384, 2048, 512, blockIdx.x, gridDim.x, nullptr);
}

// ---------------- MFMA bucketed attention, v5 + setprio (unchanged) ----------------
__global__ __launch_bounds__(512) void attn_mfma5(const u16* __restrict__ qb, const u16* __restrict__ kvb,
                                                  const u16* __restrict__ vt, u16* __restrict__ ob,
                                                  const int* __restrict__ counts, const int* __restrict__ lists){
  int bl = blockIdx.y, chunk = blockIdx.x;
  int cnt = counts[bl];
  int q0 = chunk*32;
  if (q0 >= cnt) return;
  int b = bl>>3, loc = bl&7;
  int tid = threadIdx.x, lane = tid&63, h = tid>>6;
  __shared__ u16 qs[32][520];
  int r = lane&15, g = lane>>4;

  const u16* kbase = kvb + (size_t)(b*512 + loc*64)*1024 + h*64;
  short8 kfr[4][2];
  #pragma unroll
  for (int nt=0;nt<4;++nt){
    const u16* krow = kbase + (size_t)(nt*16 + r)*1024;
    kfr[nt][0] = *(const short8*)(krow + g*8);
    kfr[nt][1] = *(const short8*)(krow + 32 + g*8);
  }
  const u16* vbase = vt + (size_t)(bl*8 + h)*4096;
  short8 vf[2][4];
  #pragma unroll
  for (int nt=0;nt<4;++nt){
    const u16* vrow = vbase + (size_t)(nt*16 + r)*64;
    vf[0][nt] = *(const short8*)(vrow + g*8);
    vf[1][nt] = *(const short8*)(vrow + 32 + g*8);
  }

  const u16* qbase = qb + (size_t)(b*4096)*512;
  #pragma unroll
  for (int p=0;p<4;++p){
    int c = p*512 + tid;
    int row = c>>6, cc = c&63;
    int qq = (q0 + row < cnt) ? lists[bl*4096 + q0 + row] : -1;
    if (qq >= 0)
      *(short8*)&qs[row][cc*8] = *(const short8*)(qbase + (size_t)qq*512 + cc*8);
  }
  __syncthreads();

  short8 qf[2][2];
  #pragma unroll
  for (int mt=0;mt<2;++mt){
    qf[mt][0] = *(const short8*)&qs[mt*16+r][h*64 + g*8];
    qf[mt][1] = *(const short8*)&qs[mt*16+r][h*64 + 32 + g*8];
  }

  f32x4 acc[2][4] = {};
  __builtin_amdgcn_s_setprio(1);
  #pragma unroll
  for (int mt=0;mt<2;++mt)
    #pragma unroll
    for (int nt=0;nt<4;++nt){
      acc[mt][nt] = __builtin_amdgcn_mfma_f32_16x16x32_bf16(qf[mt][0], kfr[nt][0], acc[mt][nt], 0,0,0);
      acc[mt][nt] = __builtin_amdgcn_mfma_f32_16x16x32_bf16(qf[mt][1], kfr[nt][1], acc[mt][nt], 0,0,0);
    }
  __builtin_amdgcn_s_setprio(0);

  #pragma unroll
  for (int mt=0;mt<2;++mt){
    #pragma unroll
    for (int rr=0;rr<4;++rr){
      float m = fmaxf(fmaxf(acc[mt][0][rr], acc[mt][1][rr]), fmaxf(acc[mt][2][rr], acc[mt][3][rr]));
      #pragma unroll
      for (int off=1;off<16;off<<=1) m = fmaxf(m, __shfl_xor(m, off));
      float e0 = __expf(acc[mt][0][rr]-m), e1 = __expf(acc[mt][1][rr]-m);
      float e2 = __expf(acc[mt][2][rr]-m), e3 = __expf(acc[mt][3][rr]-m);
      float sum = (e0+e1)+(e2+e3);
      #pragma unroll
      for (int off=1;off<16;off<<=1) sum += __shfl_xor(sum, off);
      float rs = 1.0f/sum;
      int row = mt*16 + g*4 + rr;
      qs[row][h*64 +  0 + r] = f2bf(e0*rs);
      qs[row][h*64 + 16 + r] = f2bf(e1*rs);
      qs[row][h*64 + 32 + r] = f2bf(e2*rs);
      qs[row][h*64 + 48 + r] = f2bf(e3*rs);
    }
  }

  f32x4 oacc[2][4] = {};
  #pragma unroll
  for (int mt=0;mt<2;++mt){
    short8 pa0 = *(const short8*)&qs[mt*16 + r][h*64 + g*8];
    short8 pa1 = *(const short8*)&qs[mt*16 + r][h*64 + 32 + g*8];
    __builtin_amdgcn_s_setprio(1);
    #pragma unroll
    for (int nt=0;nt<4;++nt){
      oacc[mt][nt] = __builtin_amdgcn_mfma_f32_16x16x32_bf16(pa0, vf[0][nt], oacc[mt][nt], 0,0,0);
      oacc[mt][nt] = __builtin_amdgcn_mfma_f32_16x16x32_bf16(pa1, vf[1][nt], oacc[mt][nt], 0,0,0);
    }
    __builtin_amdgcn_s_setprio(0);
  }

  #pragma unroll
  for (int mt=0;mt<2;++mt)
    #pragma unroll
    for (int rr=0;rr<4;++rr){
      int row = mt*16 + g*4 + rr;
      #pragma unroll
      for (int nt=0;nt<4;++nt)
        qs[row][h*64 + nt*16 + r] = f2bf(oacc[mt][nt][rr]);
    }
  __syncthreads();

  #pragma unroll
  for (int p=0;p<4;++p){
    int c = p*512 + tid;
    int row = c>>6, cc = c&63;
    int qq = (q0 + row < cnt) ? lists[bl*4096 + q0 + row] : -1;
    if (qq >= 0)
      *(short8*)(ob + ((size_t)(b*4096) + qq)*512 + cc*8) = *(const short8*)&qs[row][cc*8];
  }
}

extern "C" void kernel_launch(void* const* d_in, const int* in_sizes, int n_in,
                              void* d_out, int out_size, void* d_ws, size_t ws_size,
                              hipStream_t stream) {
  const float* x    = (const float*)d_in[0];
  const float* ctx  = (const float*)d_in[1];
  const int*   ml   = (const int*)d_in[2];
  const float* nw   = (const float*)d_in[3];
  const float* nb   = (const float*)d_in[4];
  const float* ncw  = (const float*)d_in[5];
  const float* ncb  = (const float*)d_in[6];
  const float* Wq   = (const float*)d_in[7];
  const float* Wkv  = (const float*)d_in[8];
  const float* Wout = (const float*)d_in[9];
  float* out = (float*)d_out;
  char* ws = (char*)d_ws;
  if (ws_size < WS_NEEDED) return;   // fail loudly (output stays poisoned)

  int* flag   = (int*)(ws + OFF_FLAG);
  int* counts = (int*)(ws + OFF_COUNTS);
  int* lists  = (int*)(ws + OFF_LISTS);
  u16* xn     = (u16*)(ws + OFF_XN);
  u16* ctxn   = (u16*)(ws + OFF_CTXN);
  u16* WqT    = (u16*)(ws + OFF_WQT);
  u16* WkvT   = (u16*)(ws + OFF_WKVT);
  u16* WoutT  = (u16*)(ws + OFF_WOUTT);
  u16* qbuf   = (u16*)(ws + OFF_Q);
  u16* kvbuf  = (u16*)(ws + OFF_KV);
  u16* attn_o = (u16*)(ws + OFF_ATTN);
  u16* vtbuf  = (u16*)(ws + OFF_VT);

  prep_all<<<21505,256,0,stream>>>(x, nw, nb, xn, ctx, ncw, ncb, ctxn,
                                   Wq, Wkv, Wout, WqT, WkvT, WoutT, ml, flag, counts);
  gemm_qkv<<<704,256,0,stream>>>(xn, WqT, qbuf, ctxn, WkvT, kvbuf, vtbuf, ml, flag, counts, lists);
  attn_mfma5<<<dim3(128,32),512,0,stream>>>(qbuf, kvbuf, vtbuf, attn_o, counts, lists);
  gemm_out<<<2048,256,0,stream>>>(attn_o, WoutT, out);
}